// Round 1
// baseline (465.542 us; speedup 1.0000x reference)
//
#include <hip/hip_runtime.h>
#include <math.h>

#define B_    8
#define C_H_  128
#define C_L_  256
#define K_    64
#define NPIX_L 16384          // 128*128
#define EPS_  1e-5f

// ws layout (float offsets)
#define P_OFF   0
#define P_SZ    (B_*K_*C_H_)      // 65536
#define CK_OFF  (P_OFF + P_SZ)
#define CK_SZ   (B_*K_*C_L_)      // 131072
#define CV_OFF  (CK_OFF + CK_SZ)
#define CV_SZ   (B_*C_L_*K_)      // 131072
#define SCL_OFF (CV_OFF + CV_SZ)
#define SHF_OFF (SCL_OFF + C_L_)

// ---------------- Kernel 1: BN + 8x8 max-pool of x_h -> p[b][k][c] ----------------
// BN is monotone: max(BN(x)) = BN(max x) if scale>=0 else BN(min x).
__global__ __launch_bounds__(256) void pool_bn_kernel(
    const float* __restrict__ x_h,
    const float* __restrict__ g, const float* __restrict__ be,
    const float* __restrict__ mn, const float* __restrict__ vr,
    float* __restrict__ ws)
{
    const int t   = threadIdx.x;
    const int k   = t & 63;        // pooled position
    const int cl  = t >> 6;        // 0..3
    const int bid = blockIdx.x;    // 256 blocks = 8 b * 32 cgroups
    const int b   = bid >> 5;
    const int c   = ((bid & 31) << 2) + cl;

    const float* plane = x_h + ((size_t)(b * C_H_ + c) << 12);   // *4096
    const int ph = k >> 3, pw = k & 7;
    const float* p0 = plane + (ph * 8) * 64 + pw * 8;

    float mx = -INFINITY, mnv = INFINITY;
#pragma unroll
    for (int i = 0; i < 8; i++) {
        const float4 a  = *reinterpret_cast<const float4*>(p0 + i * 64);
        const float4 bq = *reinterpret_cast<const float4*>(p0 + i * 64 + 4);
        mx  = fmaxf(mx,  fmaxf(fmaxf(a.x, a.y),  fmaxf(a.z, a.w)));
        mx  = fmaxf(mx,  fmaxf(fmaxf(bq.x, bq.y), fmaxf(bq.z, bq.w)));
        mnv = fminf(mnv, fminf(fminf(a.x, a.y),  fminf(a.z, a.w)));
        mnv = fminf(mnv, fminf(fminf(bq.x, bq.y), fminf(bq.z, bq.w)));
    }
    const float sc  = g[c] * rsqrtf(vr[c] + EPS_);
    const float sel = (sc >= 0.f) ? mx : mnv;
    const float pv  = fmaf(sel - mn[c], sc, be[c]);
    ws[P_OFF + (b * K_ + k) * C_H_ + c] = pv;
}

// ---------------- Kernel 2: kv projection -> ck[b][k][c], cv[b][c][k]; BN-l coeffs ----------------
__global__ __launch_bounds__(256) void kv_kernel(
    const float* __restrict__ kv_w, const float* __restrict__ kv_b,
    const float* __restrict__ lg, const float* __restrict__ lb,
    const float* __restrict__ lm, const float* __restrict__ lv,
    float* __restrict__ ws)
{
    __shared__ __align__(16) float prow[C_H_];
    const int t   = threadIdx.x;
    const int bid = blockIdx.x;          // 512 blocks = 8 b * 64 k
    const int b   = bid >> 6;
    const int k   = bid & 63;

    if (t < C_H_ / 4) {
        reinterpret_cast<float4*>(prow)[t] =
            reinterpret_cast<const float4*>(ws + P_OFF + (b * K_ + k) * C_H_)[t];
    }
    __syncthreads();

    float a0 = kv_b[t];
    float a1 = kv_b[t + 256];
    const float* w0 = kv_w + (size_t)t * C_H_;
    const float* w1 = kv_w + (size_t)(t + 256) * C_H_;
#pragma unroll
    for (int c = 0; c < C_H_; c += 4) {
        const float4 pv  = *reinterpret_cast<const float4*>(prow + c);
        const float4 wv0 = *reinterpret_cast<const float4*>(w0 + c);
        const float4 wv1 = *reinterpret_cast<const float4*>(w1 + c);
        a0 = fmaf(wv0.x, pv.x, a0); a0 = fmaf(wv0.y, pv.y, a0);
        a0 = fmaf(wv0.z, pv.z, a0); a0 = fmaf(wv0.w, pv.w, a0);
        a1 = fmaf(wv1.x, pv.x, a1); a1 = fmaf(wv1.y, pv.y, a1);
        a1 = fmaf(wv1.z, pv.z, a1); a1 = fmaf(wv1.w, pv.w, a1);
    }
    ws[CK_OFF + (b * K_ + k) * C_L_ + t] = a0;
    ws[CV_OFF + (b * C_L_ + t) * K_ + k] = a1;

    if (bid == 0) {   // BN-l scale/shift precompute (once; kernel3 runs after)
        const float s = lg[t] * rsqrtf(lv[t] + EPS_);
        ws[SCL_OFF + t] = s;
        ws[SHF_OFF + t] = fmaf(-lm[t], s, lb[t]);
    }
}

// ---------------- Kernel 3: attention + softmax + PV + residual ----------------
// 256 blocks (b = bid%8 -> XCD-pinned), 256 threads, 2 pixels/thread (512 pix/block).
__global__ __launch_bounds__(256, 1) void attn_kernel(
    const float* __restrict__ x_l,
    const float* __restrict__ reatt,
    const float* __restrict__ ws,
    float* __restrict__ out)
{
    __shared__ __align__(16) float mat[K_ * C_L_];   // 64 KB: ck in phase A, cv in phase B
    const int t    = threadIdx.x;
    const int bid  = blockIdx.x;
    const int b    = bid & 7;
    const int tile = bid >> 3;                       // 0..31
    const int p0   = tile * 512 + t;                 // pixel A; pixel B = p0+256

    // stage ck[b] (64x256 floats) into LDS
    {
        const float4* src = reinterpret_cast<const float4*>(ws + CK_OFF + b * (K_ * C_L_));
        float4* dst = reinterpret_cast<float4*>(mat);
#pragma unroll
        for (int i = 0; i < 16; i++) dst[t + 256 * i] = src[t + 256 * i];
    }

    const float* scl = ws + SCL_OFF;
    const float* shf = ws + SHF_OFF;
    const float* xb  = x_l + (size_t)b * (C_L_ * NPIX_L) + p0;

    float acc0[K_], acc1[K_];
#pragma unroll
    for (int k = 0; k < K_; k++) { acc0[k] = 0.f; acc1[k] = 0.f; }

    __syncthreads();

    // ---- phase A: logits (c ascending) ----
    float xa0[4], xa1[4];
#pragma unroll
    for (int j = 0; j < 4; j++) { xa0[j] = xb[j * NPIX_L]; xa1[j] = xb[j * NPIX_L + 256]; }

    for (int cc = 0; cc < C_L_; cc += 4) {
        // prefetch next group (clamped; garbage-reuse at the tail is never consumed)
        const int ncc = (cc + 4 < C_L_) ? (cc + 4) : cc;
        const float* nx = xb + ncc * NPIX_L;
        float nb0[4], nb1[4];
#pragma unroll
        for (int j = 0; j < 4; j++) { nb0[j] = nx[j * NPIX_L]; nb1[j] = nx[j * NPIX_L + 256]; }

        float xs0[4], xs1[4];
#pragma unroll
        for (int j = 0; j < 4; j++) {
            const float s = scl[cc + j], h = shf[cc + j];
            xs0[j] = fmaf(xa0[j], s, h);
            xs1[j] = fmaf(xa1[j], s, h);
        }
#pragma unroll
        for (int k = 0; k < K_; k++) {
            const float4 ckv = *reinterpret_cast<const float4*>(&mat[k * C_L_ + cc]);
            float t0 = acc0[k];
            t0 = fmaf(ckv.x, xs0[0], t0); t0 = fmaf(ckv.y, xs0[1], t0);
            t0 = fmaf(ckv.z, xs0[2], t0); t0 = fmaf(ckv.w, xs0[3], t0);
            acc0[k] = t0;
            float t1 = acc1[k];
            t1 = fmaf(ckv.x, xs1[0], t1); t1 = fmaf(ckv.y, xs1[1], t1);
            t1 = fmaf(ckv.z, xs1[2], t1); t1 = fmaf(ckv.w, xs1[3], t1);
            acc1[k] = t1;
        }
#pragma unroll
        for (int j = 0; j < 4; j++) { xa0[j] = nb0[j]; xa1[j] = nb1[j]; }
    }

    // ---- softmax over k (in registers) ----
    float m0 = -INFINITY, m1 = -INFINITY;
#pragma unroll
    for (int k = 0; k < K_; k++) {
        const float rk = reatt[k];
        acc0[k] = (acc0[k] + rk) * 0.125f;
        acc1[k] = (acc1[k] + rk) * 0.125f;
        m0 = fmaxf(m0, acc0[k]);
        m1 = fmaxf(m1, acc1[k]);
    }
    float s0 = 0.f, s1 = 0.f;
#pragma unroll
    for (int k = 0; k < K_; k++) {
        const float e0 = __expf(acc0[k] - m0); acc0[k] = e0; s0 += e0;
        const float e1 = __expf(acc1[k] - m1); acc1[k] = e1; s1 += e1;
    }
    const float r0 = 1.f / s0, r1 = 1.f / s1;
#pragma unroll
    for (int k = 0; k < K_; k++) { acc0[k] *= r0; acc1[k] *= r1; }

    __syncthreads();
    // stage cv[b] (256x64 floats) into LDS
    {
        const float4* src = reinterpret_cast<const float4*>(ws + CV_OFF + b * (C_L_ * K_));
        float4* dst = reinterpret_cast<float4*>(mat);
#pragma unroll
        for (int i = 0; i < 16; i++) dst[t + 256 * i] = src[t + 256 * i];
    }
    __syncthreads();

    // ---- phase B: out = x_l + cv . w  (c descending for L2 reuse of phase-A tail) ----
    float* ob = out + (size_t)b * (C_L_ * NPIX_L) + p0;
    float xr0 = xb[(C_L_ - 1) * NPIX_L], xr1 = xb[(C_L_ - 1) * NPIX_L + 256];
    for (int c = C_L_ - 1; c >= 0; c--) {
        const int pc = (c > 0) ? (c - 1) : 0;
        const float nr0 = xb[pc * NPIX_L];
        const float nr1 = xb[pc * NPIX_L + 256];
        float pa0 = 0.f, pb0 = 0.f, pc0 = 0.f, pd0 = 0.f;
        float pa1 = 0.f, pb1 = 0.f, pc1 = 0.f, pd1 = 0.f;
#pragma unroll
        for (int kk = 0; kk < K_; kk += 4) {
            const float4 cvv = *reinterpret_cast<const float4*>(&mat[c * K_ + kk]);
            pa0 = fmaf(cvv.x, acc0[kk],     pa0);
            pb0 = fmaf(cvv.y, acc0[kk + 1], pb0);
            pc0 = fmaf(cvv.z, acc0[kk + 2], pc0);
            pd0 = fmaf(cvv.w, acc0[kk + 3], pd0);
            pa1 = fmaf(cvv.x, acc1[kk],     pa1);
            pb1 = fmaf(cvv.y, acc1[kk + 1], pb1);
            pc1 = fmaf(cvv.z, acc1[kk + 2], pc1);
            pd1 = fmaf(cvv.w, acc1[kk + 3], pd1);
        }
        const float o0 = xr0 + ((pa0 + pb0) + (pc0 + pd0));
        const float o1 = xr1 + ((pa1 + pb1) + (pc1 + pd1));
        __builtin_nontemporal_store(o0, ob + c * NPIX_L);
        __builtin_nontemporal_store(o1, ob + c * NPIX_L + 256);
        xr0 = nr0; xr1 = nr1;
    }
}

extern "C" void kernel_launch(void* const* d_in, const int* in_sizes, int n_in,
                              void* d_out, int out_size, void* d_ws, size_t ws_size,
                              hipStream_t stream) {
    const float* x_h  = (const float*)d_in[0];
    const float* x_l  = (const float*)d_in[1];
    const float* hg   = (const float*)d_in[2];
    const float* hb   = (const float*)d_in[3];
    const float* hm   = (const float*)d_in[4];
    const float* hv   = (const float*)d_in[5];
    const float* kvw  = (const float*)d_in[6];
    const float* kvb  = (const float*)d_in[7];
    const float* lg   = (const float*)d_in[8];
    const float* lb   = (const float*)d_in[9];
    const float* lm   = (const float*)d_in[10];
    const float* lv   = (const float*)d_in[11];
    const float* ratt = (const float*)d_in[12];
    float* ws  = (float*)d_ws;
    float* out = (float*)d_out;

    pool_bn_kernel<<<256, 256, 0, stream>>>(x_h, hg, hb, hm, hv, ws);
    kv_kernel<<<512, 256, 0, stream>>>(kvw, kvb, lg, lb, lm, lv, ws);
    attn_kernel<<<256, 256, 0, stream>>>(x_l, ratt, ws, out);
}